// Round 4
// baseline (1382.674 us; speedup 1.0000x reference)
//
#include <hip/hip_runtime.h>
#include <math.h>

#define LL 64
#define BB 8
#define HH 512
#define H2 1024
#define VV 8192
#define NSENT 63
#define NPAIR 2016          // i<j pairs
#define NPITEM 2017         // + root (0,0)
#define MROWS 16136         // 2017*8
#define MPAD 16256          // 127*128
#define NEGV (-1e9f)
#define EPSV 4.5399929762484854e-05f

typedef unsigned int uint;
typedef unsigned short ushort;
using bf16x8 = __attribute__((ext_vector_type(8))) short;
using f32x4  = __attribute__((ext_vector_type(4))) float;

__device__ inline ushort f2bf(float x) {   // round-to-nearest-even
    uint u = __float_as_uint(x);
    uint r = (u + 0x7fffu + ((u >> 16) & 1u)) >> 16;
    return (ushort)r;
}
__device__ inline float bf2f(ushort x) {
    uint u = ((uint)x) << 16;
    return __uint_as_float(u);
}
// staged (MFMA-fragment-order) offset in ushorts for element (row, k), K=512:
// slab = 16 rows x 32 k = 512 ushorts, lane-ordered: quad=k>>3 chunk, l15=row&15
__device__ inline size_t staged_off(int row, int k) {
    return ((size_t)(row >> 4) << 13) + ((size_t)(k >> 5) << 9)
         + (((k >> 3) & 3) << 7) + ((row & 15) << 3) + (k & 7);
}
__device__ inline void gl_lds16(const ushort* g, ushort* l) {
    __builtin_amdgcn_global_load_lds(
        (const __attribute__((address_space(1))) unsigned int*)g,
        (__attribute__((address_space(3))) unsigned int*)l, 16, 0, 0);
}

// ---------------------------------------------------------------- init table
__global__ __launch_bounds__(256) void init_table_kernel(float* __restrict__ table) {
    table[blockIdx.x * 256 + threadIdx.x] = NEGV;
}

// ---------------------------------------------------------------- pair tables + words + dp counters
__global__ __launch_bounds__(256) void pairtab_kernel(
    const int* __restrict__ sentence, int* __restrict__ pair_i,
    int* __restrict__ pair_j, int* __restrict__ words, uint* __restrict__ cnt)
{
    const int p = blockIdx.x * 256 + threadIdx.x;
    if (blockIdx.x == 0 && threadIdx.x < 64) cnt[threadIdx.x] = 0;
    if (p >= NPITEM) return;
    int i = 0, j = 0;
    if (p == NPAIR) { i = 0; j = 0; }
    else {
        int base = 0;
        while (i < 62 && p >= base + (NSENT - i)) { base += NSENT - i; i++; }
        j = i + 1 + (p - base);
    }
    pair_i[p] = i; pair_j[p] = j;
    for (int b = 0; b < BB; b++) {
        int w;
        if (p == NPAIR)      w = sentence[1 * BB + b];
        else if (j <= 62)    w = sentence[(j + 1) * BB + b];
        else                 w = -1;
        words[p * BB + b] = w;
    }
}

// ---------------------------------------------------------------- U/L factor GEMMs
__global__ __launch_bounds__(256) void ul_kernel(
    const float* __restrict__ enc, const float* __restrict__ W1t,
    const float* __restrict__ W1w, float* __restrict__ UL)
{
    const int mat = blockIdx.x >> 6;
    const int l = blockIdx.x & 63;
    __shared__ float f[BB][HH];    // 16 KB
    for (int t = threadIdx.x; t < BB * HH; t += 256)
        f[t >> 9][t & 511] = enc[(size_t)l * BB * HH + t];
    __syncthreads();

    const float* W = (mat == 0) ? W1t : (mat == 1) ? (W1t + HH * HH)
                   : (mat == 2) ? W1w : (W1w + HH * HH);
    const int u0 = threadIdx.x;
    float acc0[BB], acc1[BB];
#pragma unroll
    for (int b = 0; b < BB; b++) { acc0[b] = 0.f; acc1[b] = 0.f; }
    for (int k = 0; k < HH; k += 4) {
        float4 fk[BB];
#pragma unroll
        for (int b = 0; b < BB; b++) fk[b] = *(const float4*)&f[b][k];
#pragma unroll
        for (int kk = 0; kk < 4; kk++) {
            float w0 = W[(size_t)(k + kk) * HH + u0];
            float w1 = W[(size_t)(k + kk) * HH + u0 + 256];
#pragma unroll
            for (int b = 0; b < BB; b++) {
                float fb = ((const float*)&fk[b])[kk];
                acc0[b] = fmaf(fb, w0, acc0[b]);
                acc1[b] = fmaf(fb, w1, acc1[b]);
            }
        }
    }
    float* out = UL + (size_t)mat * 512 * 512 + (size_t)(l * BB) * HH;
#pragma unroll
    for (int b = 0; b < BB; b++) {
        out[b * HH + u0]       = acc0[b];
        out[b * HH + u0 + 256] = acc1[b];
    }
}

// ---------------------------------------------------------------- W2w -> bf16 staged [n][k]
__global__ __launch_bounds__(256) void w2wt_kernel(
    const float* __restrict__ W2w, ushort* __restrict__ w2wT)
{
    const int kt = blockIdx.x >> 7;      // 0..7   (K tiles of 64)
    const int nt = blockIdx.x & 127;     // 0..127 (N tiles of 64)
    const int k0 = kt * 64, n0 = nt * 64;
    __shared__ float tile[64][65];
    for (int it = 0; it < 16; it++) {
        int idx = it * 256 + threadIdx.x;
        int kr = idx >> 6, nc = idx & 63;
        tile[kr][nc] = W2w[(size_t)(k0 + kr) * VV + n0 + nc];
    }
    __syncthreads();
    // 64 n x 32 k-pairs = 2048 uint stores
    for (int it = 0; it < 8; it++) {
        int idx = it * 256 + threadIdx.x;
        int nr = idx >> 5, kp = idx & 31;
        int kc = kp * 2;
        uint v = (uint)f2bf(tile[kc][nr]) | ((uint)f2bf(tile[kc + 1][nr]) << 16);
        *(uint*)&w2wT[staged_off(n0 + nr, k0 + kc)] = v;
    }
}

// ---------------------------------------------------------------- per-pair: trans probs + hidden_w (bf16 staged)
__global__ __launch_bounds__(256) void pairs_kernel(
    const float* __restrict__ UL, const float* __restrict__ b1t,
    const float* __restrict__ W2t, const float* __restrict__ b2t,
    const float* __restrict__ b1w, const int* __restrict__ pair_i,
    const int* __restrict__ pair_j, float* __restrict__ sh_log,
    float* __restrict__ red_log, ushort* __restrict__ hbf)
{
    const int p = blockIdx.x;
    const int i = pair_i[p], j = pair_j[p];
    const float* Ut = UL;
    const float* Lt = UL + 512 * 512;
    const float* Uw = UL + 2 * 512 * 512;
    const float* Lw = UL + 3 * 512 * 512;

    __shared__ float redm[4][BB];
    const int k0 = threadIdx.x * 2;
    const float2 b1wv = *(const float2*)&b1w[k0];
    const float2 b1tv = *(const float2*)&b1t[k0];
    const float2 w2tv = *(const float2*)&W2t[k0];
    const size_t kpart = ((size_t)(k0 >> 5) << 9) + (((k0 >> 3) & 3) << 7) + (k0 & 7);

    float part[BB];
#pragma unroll
    for (int b = 0; b < BB; b++) {
        const int row = p * BB + b;
        // word hidden
        float2 u = *(const float2*)&Uw[(size_t)(i * BB + b) * HH + k0];
        float2 l = *(const float2*)&Lw[(size_t)(j * BB + b) * HH + k0];
        float h0 = u.x + l.x + b1wv.x; h0 = h0 > 0.f ? h0 : 0.f;
        float h1 = u.y + l.y + b1wv.y; h1 = h1 > 0.f ? h1 : 0.f;
        uint packed = (uint)f2bf(h0) | ((uint)f2bf(h1) << 16);
        *(uint*)&hbf[((size_t)(row >> 4) << 13) + kpart + ((row & 15) << 3)] = packed;
        // trans hidden -> partial score
        float2 ut = *(const float2*)&Ut[(size_t)(i * BB + b) * HH + k0];
        float2 lt = *(const float2*)&Lt[(size_t)(j * BB + b) * HH + k0];
        float t0 = ut.x + lt.x + b1tv.x; t0 = t0 > 0.f ? t0 : 0.f;
        float t1 = ut.y + lt.y + b1tv.y; t1 = t1 > 0.f ? t1 : 0.f;
        part[b] = t0 * w2tv.x + t1 * w2tv.y;
    }
    if (p == NPAIR) return;   // root: no trans

#pragma unroll
    for (int off = 32; off > 0; off >>= 1)
#pragma unroll
        for (int b = 0; b < BB; b++) part[b] += __shfl_down(part[b], off, 64);
    const int wave = threadIdx.x >> 6, lane = threadIdx.x & 63;
    if (lane == 0)
#pragma unroll
        for (int b = 0; b < BB; b++) redm[wave][b] = part[b];
    __syncthreads();
    if (threadIdx.x < BB) {
        const int b = threadIdx.x;
        float sc = redm[0][b] + redm[1][b] + redm[2][b] + redm[3][b] + b2t[0];
        float pr = 1.f / (1.f + expf(-sc));
        sh_log[(i * LL + j) * BB + b]  = log1pf(-pr + EPSV);
        red_log[(i * LL + j) * BB + b] = logf(pr + EPSV);
    }
}

// ---------------------------------------------------------------- logits GEMM (MFMA, glds staging) + exp-sum partials
__global__ __launch_bounds__(256) void gemm_kernel(
    const ushort* __restrict__ hA, const ushort* __restrict__ w2wT,
    const float* __restrict__ b2w, float* __restrict__ part_s)
{
    const int mt = blockIdx.x >> 6;      // 0..126
    const int nt = blockIdx.x & 63;      // 0..63
    __shared__ ushort As[8192];          // 16 KB: 16 slabs of 512 (rt*2+kt)
    __shared__ ushort Bs[8192];

    const int tid = threadIdx.x;
    const int lane = tid & 63, w = tid >> 6;
    const int wm = w >> 1, wn = w & 1;
    const int quad = lane >> 4, l15 = lane & 15;

    f32x4 acc[4][4];
#pragma unroll
    for (int a = 0; a < 4; a++)
#pragma unroll
        for (int b = 0; b < 4; b++) acc[a][b] = (f32x4){0.f, 0.f, 0.f, 0.f};

    for (int kc = 0; kc < 8; kc++) {
        __syncthreads();
        // 32 slabs (16 A + 16 B), 8 per wave, one global_load_lds_dwordx4 each
#pragma unroll
        for (int s = 0; s < 8; s++) {
            const int slab = w * 8 + s;
            const int sl = slab & 15;
            const int rt = sl >> 1, t = sl & 1;
            if (slab < 16) {
                const ushort* g = hA + ((size_t)(mt * 8 + rt) << 13)
                                + ((size_t)(2 * kc + t) << 9) + lane * 8;
                gl_lds16(g, &As[sl * 512]);
            } else {
                const ushort* g = w2wT + ((size_t)(nt * 8 + rt) << 13)
                                + ((size_t)(2 * kc + t) << 9) + lane * 8;
                gl_lds16(g, &Bs[sl * 512]);
            }
        }
        __syncthreads();
#pragma unroll
        for (int ks = 0; ks < 2; ks++) {
            bf16x8 af[4], bfr[4];
#pragma unroll
            for (int fm = 0; fm < 4; fm++)
                af[fm] = *(const bf16x8*)&As[((wm * 4 + fm) * 2 + ks) * 512 + lane * 8];
#pragma unroll
            for (int fn = 0; fn < 4; fn++)
                bfr[fn] = *(const bf16x8*)&Bs[((wn * 4 + fn) * 2 + ks) * 512 + lane * 8];
#pragma unroll
            for (int fm = 0; fm < 4; fm++)
#pragma unroll
                for (int fn = 0; fn < 4; fn++)
                    acc[fm][fn] = __builtin_amdgcn_mfma_f32_16x16x32_bf16(
                        af[fm], bfr[fn], acc[fm][fn], 0, 0, 0);
        }
    }

    // epilogue: unstabilized exp-sum over this wave's 64 cols (logits are O(1))
    float bias[4];
#pragma unroll
    for (int fn = 0; fn < 4; fn++)
        bias[fn] = b2w[nt * 128 + wn * 64 + fn * 16 + l15];
    const int pslot = nt * 2 + wn;
#pragma unroll
    for (int fm = 0; fm < 4; fm++) {
#pragma unroll
        for (int r = 0; r < 4; r++) {
            float s = __expf(acc[fm][0][r] + bias[0]) + __expf(acc[fm][1][r] + bias[1])
                    + __expf(acc[fm][2][r] + bias[2]) + __expf(acc[fm][3][r] + bias[3]);
            s += __shfl_xor(s, 1, 64);
            s += __shfl_xor(s, 2, 64);
            s += __shfl_xor(s, 4, 64);
            s += __shfl_xor(s, 8, 64);
            if (l15 == 0) {
                const int grow = mt * 128 + wm * 64 + fm * 16 + quad * 4 + r;
                part_s[(size_t)pslot * MPAD + grow] = s;
            }
        }
    }
}

// ---------------------------------------------------------------- gval: logit of the target word (wave per row)
__global__ __launch_bounds__(256) void gval_kernel(
    const ushort* __restrict__ hA, const ushort* __restrict__ w2wT,
    const float* __restrict__ b2w, const int* __restrict__ words,
    float* __restrict__ gval)
{
    const int wave = threadIdx.x >> 6, lane = threadIdx.x & 63;
    const int row = blockIdx.x * 4 + wave;
    if (row >= MROWS) return;
    const int word = words[row];
    if (word < 0) return;
    const int k0 = lane * 8;
    const ushort* hp = hA + staged_off(row, k0);
    const ushort* wp = w2wT + staged_off(word, k0);
    float d = 0.f;
#pragma unroll
    for (int c = 0; c < 8; c++)
        d = fmaf(bf2f(hp[c]), bf2f(wp[c]), d);
#pragma unroll
    for (int off = 32; off > 0; off >>= 1) d += __shfl_down(d, off, 64);
    if (lane == 0) gval[row] = d + b2w[word];
}

// ---------------------------------------------------------------- combine exp-sum partials -> base cells
__global__ __launch_bounds__(256) void combine_kernel(
    const float* __restrict__ part_s, const float* __restrict__ gval,
    const float* __restrict__ sh_log, const int* __restrict__ pair_i,
    const int* __restrict__ pair_j, float* __restrict__ table)
{
    const int row = blockIdx.x * 256 + threadIdx.x;
    if (row >= MROWS) return;
    const int p = row >> 3, b = row & 7;
    float S = 0.f;
    for (int nt = 0; nt < 128; nt++)
        S += part_s[(size_t)nt * MPAD + row];
    const float lse = logf(S);
    const float g = gval[row] - lse;
    const int i = pair_i[p], j = pair_j[p];
    if (p == NPAIR) {
        table[(size_t)((0 * LL + 0) * LL + 1) * BB + b] = g;
    } else if (j <= 62) {
        table[(size_t)((i * LL + j) * LL + (j + 1)) * BB + b] =
            sh_log[(i * LL + j) * BB + b] + g;
    }
}

// ---------------------------------------------------------------- persistent DP: all 62 levels, grid barrier between
__global__ __launch_bounds__(256) void dp_all_kernel(
    const float* __restrict__ red_log, float* table, uint* cnt, float* out)
{
    const int tid = threadIdx.x;
    const int nb = gridDim.x;

    for (int gap = 2; gap <= NSENT; gap++) {
        const int I = LL - gap;
        const int total = LL * I * BB * 4;   // split-k x4
        for (int t4 = blockIdx.x * 256 + tid; t4 < total; t4 += nb * 256) {
            const int item = t4 >> 2, sub = t4 & 3;
            const int b = item & 7;
            const int t = item >> 3;
            const int i = t % I;
            const int l = t / I;
            const int j = i + gap;

            const float* tli = table + (size_t)(l * LL + i) * LL * BB + b;
            const float* tij = table + ((size_t)i * LL * LL + j) * BB + b;
            const float* rl  = red_log + (size_t)j * BB + b;

            float m = -3.4e38f, s = 0.f;
            for (int k = i + 1 + sub; k < j; k += 4) {
                float x = tli[k * BB] + tij[k * (LL * BB)] + rl[k * (LL * BB)];
                if (x > m) { s = s * __expf(m - x) + 1.f; m = x; }
                else       { s += __expf(x - m); }
            }
#pragma unroll
            for (int off = 1; off <= 2; off <<= 1) {
                float mo = __shfl_xor(m, off, 64);
                float so = __shfl_xor(s, off, 64);
                float M = fmaxf(m, mo);
                s = s * __expf(m - M) + so * __expf(mo - M);
                m = M;
            }
            if (sub == 0)
                table[(((size_t)l * LL + i) * LL + j) * BB + b] = m + logf(s);
        }
        // grid barrier (agent scope; release stores -> L2 wb, acquire -> inv)
        __syncthreads();
        if (tid == 0) {
            __threadfence();
            __hip_atomic_fetch_add(&cnt[gap], 1u, __ATOMIC_ACQ_REL, __HIP_MEMORY_SCOPE_AGENT);
            long spins = 0;
            while (__hip_atomic_load(&cnt[gap], __ATOMIC_ACQUIRE,
                                     __HIP_MEMORY_SCOPE_AGENT) < (uint)nb) {
                if (++spins > (1L << 22)) break;   // safety: all blocks are co-resident
            }
            __threadfence();
        }
        __syncthreads();
    }
    if (blockIdx.x == 0 && tid < BB)
        out[tid] = table[(size_t)(0 * LL * LL + NSENT) * BB + tid];
}

// ---------------------------------------------------------------- launch
extern "C" void kernel_launch(void* const* d_in, const int* in_sizes, int n_in,
                              void* d_out, int out_size, void* d_ws, size_t ws_size,
                              hipStream_t stream) {
    const float* enc      = (const float*)d_in[0];
    const int*   sentence = (const int*)  d_in[1];
    const float* W1t      = (const float*)d_in[2];
    const float* b1t      = (const float*)d_in[3];
    const float* W2t      = (const float*)d_in[4];
    const float* b2t      = (const float*)d_in[5];
    const float* W1w      = (const float*)d_in[6];
    const float* b1w      = (const float*)d_in[7];
    const float* W2w      = (const float*)d_in[8];
    const float* b2w      = (const float*)d_in[9];
    float* out = (float*)d_out;

    float* base = (float*)d_ws;
    float* table   = base;                 base += (size_t)LL * LL * LL * BB;   // 2,097,152
    float* sh_log  = base;                 base += LL * LL * BB;
    float* red_log = base;                 base += LL * LL * BB;
    float* UL      = base;                 base += 4 * 512 * 512;
    float* part_s  = base;                 base += (size_t)128 * MPAD;
    float* gval    = base;                 base += MPAD;
    int*   words   = (int*)base;           base += MPAD;
    int*   pair_i  = (int*)base;           base += 2048;
    int*   pair_j  = (int*)base;           base += 2048;
    uint*  cnt     = (uint*)base;          base += 64;
    ushort* hbf    = (ushort*)base;        base += (size_t)MPAD * HH / 2;
    ushort* w2wT   = (ushort*)base;        base += (size_t)VV * HH / 2;

    init_table_kernel<<<(LL * LL * LL * BB) / 256, 256, 0, stream>>>(table);
    pairtab_kernel<<<8, 256, 0, stream>>>(sentence, pair_i, pair_j, words, cnt);
    ul_kernel<<<256, 256, 0, stream>>>(enc, W1t, W1w, UL);
    w2wt_kernel<<<1024, 256, 0, stream>>>(W2w, w2wT);
    pairs_kernel<<<NPITEM, 256, 0, stream>>>(UL, b1t, W2t, b2t, b1w,
                                             pair_i, pair_j, sh_log, red_log, hbf);
    gemm_kernel<<<127 * 64, 256, 0, stream>>>(hbf, w2wT, b2w, part_s);
    gval_kernel<<<(MROWS + 3) / 4, 256, 0, stream>>>(hbf, w2wT, b2w, words, gval);
    combine_kernel<<<64, 256, 0, stream>>>(part_s, gval, sh_log, pair_i, pair_j, table);
    dp_all_kernel<<<64, 256, 0, stream>>>(red_log, table, cnt, out);
}